// Round 7
// baseline (291.938 us; speedup 1.0000x reference)
//
#include <hip/hip_runtime.h>
#include <stdint.h>

#define N_TOT 16384
#define LNEI  32
#define DM    256
#define NH    8
#define DH    32
#define DFF   1024

typedef __attribute__((ext_vector_type(8))) short  short8;
typedef __attribute__((ext_vector_type(4))) float  floatx4;
typedef __attribute__((ext_vector_type(4))) unsigned short ushort4_t;
typedef __attribute__((ext_vector_type(4))) unsigned int uint4_t;

static __device__ __forceinline__ float b2f(unsigned short u) {
  union { unsigned int u; float f; } x; x.u = ((unsigned int)u) << 16; return x.f;
}
static __device__ __forceinline__ unsigned short f2b(float f) {
  union { float f; unsigned int u; } x; x.f = f;
  unsigned int r = x.u + 0x7fffu + ((x.u >> 16) & 1u);
  return (unsigned short)(r >> 16);
}
static __device__ __forceinline__ float lo16(unsigned int d) {
  union { unsigned int u; float f; } x; x.u = d << 16; return x.f;
}
static __device__ __forceinline__ float hi16(unsigned int d) {
  union { unsigned int u; float f; } x; x.u = d & 0xffff0000u; return x.f;
}

// -------- conversion pass: f32 -> bf16 into ws (strided dst, src=null -> 0) --
#define NSEG 11
struct Seg { const float* src; unsigned short* dst; int cols; int ostride; int ooff; int begin; };
struct SegTable { Seg s[NSEG]; int total; };

__global__ __launch_bounds__(256) void cvt_all(SegTable T, float* biaskv,
                                               const float* bkc, const float* bkp,
                                               const float* bv) {
  int e = (blockIdx.x * 256 + threadIdx.x) * 4;
  if (e >= T.total) {                       // trailing block: bias concat
    int c = e - T.total;
    #pragma unroll
    for (int j = 0; j < 4; ++j, ++c)
      if (c < 512) biaskv[c] = (c < 256) ? (bkc[c] + bkp[c]) : bv[c - 256];
    return;
  }
  int si = 0;
  #pragma unroll
  for (int i = 1; i < NSEG; ++i) if (e >= T.s[i].begin) si = i;
  const Seg s = T.s[si];
  const int le = e - s.begin;
  const int row = le / s.cols;
  const int col = le - row * s.cols;
  floatx4 v = {0.f, 0.f, 0.f, 0.f};
  if (s.src) v = *(const floatx4*)(s.src + le);
  ushort4_t o;
  o.x = f2b(v[0]); o.y = f2b(v[1]); o.z = f2b(v[2]); o.w = f2b(v[3]);
  *(ushort4_t*)(s.dst + (size_t)row * s.ostride + s.ooff + col) = o;
}

static __device__ __forceinline__ void gl_lds16(const unsigned short* g, unsigned short* l) {
  __builtin_amdgcn_global_load_lds(
      (const __attribute__((address_space(1))) unsigned int*)g,
      (__attribute__((address_space(3))) unsigned int*)l, 16, 0, 0);
}

// -------- 1-wave GEMM: BM=32, BN=64, BK=32x2. 64 threads/block. ------------
// Grid (M/32, Nd/64) = 2048-4096 blocks -> 8-13 independent waves/CU, each
// its own barrier domain (single-wave __syncthreads ~ waitcnt only).
// MFMA 16x16x32; A-frag lane: A[r=l16][k=quad*8..+8]; C/D col=l16, row=quad*4+i.
template<bool RELU>
__global__ __launch_bounds__(64) void gemm_w1(
    const unsigned short* __restrict__ A, const unsigned short* __restrict__ W,
    const float* __restrict__ bias,
    unsigned short* __restrict__ C, int M, int Nd, int K, int lda)
{
  constexpr int BK = 32;
  __shared__ unsigned short sA[2][32 * BK];
  __shared__ unsigned short sB[2][64 * BK];

  const int lane = threadIdx.x;
  const int quad = lane >> 4;
  const int l16  = lane & 15;
  const int m0 = blockIdx.x * 32;
  const int n0 = blockIdx.y * 64;

  const int srow = lane >> 2;          // staging: chunk flat = c*512 + lane*8
  const int scol = (lane & 3) * 8;     // row = c*16 + lane>>2, col = (lane&3)*8

  floatx4 acc[2][4] = {};

  for (int k0 = 0; k0 < K; k0 += 2 * BK) {
    __syncthreads();
    #pragma unroll
    for (int half = 0; half < 2; ++half) {
      const int kk = k0 + half * BK;
      #pragma unroll
      for (int c = 0; c < 2; ++c)
        gl_lds16(A + (size_t)(m0 + c * 16 + srow) * lda + kk + scol, &sA[half][c * 512]);
      #pragma unroll
      for (int c = 0; c < 4; ++c)
        gl_lds16(W + (size_t)(n0 + c * 16 + srow) * K + kk + scol, &sB[half][c * 512]);
    }
    __syncthreads();

    #pragma unroll
    for (int half = 0; half < 2; ++half) {
      short8 af[2], bf[4];
      #pragma unroll
      for (int mi = 0; mi < 2; ++mi)
        af[mi] = *(const short8*)&sA[half][(mi * 16 + l16) * BK + quad * 8];
      #pragma unroll
      for (int ni = 0; ni < 4; ++ni)
        bf[ni] = *(const short8*)&sB[half][(ni * 16 + l16) * BK + quad * 8];
      #pragma unroll
      for (int mi = 0; mi < 2; ++mi)
        #pragma unroll
        for (int ni = 0; ni < 4; ++ni)
          acc[mi][ni] = __builtin_amdgcn_mfma_f32_16x16x32_bf16(af[mi], bf[ni], acc[mi][ni], 0, 0, 0);
    }
  }

  #pragma unroll
  for (int ni = 0; ni < 4; ++ni) {
    const int col = n0 + ni * 16 + l16;
    const float bvv = bias[col];
    #pragma unroll
    for (int mi = 0; mi < 2; ++mi) {
      const int row0 = m0 + mi * 16 + quad * 4;
      #pragma unroll
      for (int i = 0; i < 4; ++i) {
        float v = acc[mi][ni][i] + bvv;
        if (RELU) v = fmaxf(v, 0.f);
        C[(size_t)(row0 + i) * Nd + col] = f2b(v);
      }
    }
  }
}

// -------- 4-wave GEMM for W1 (BN=128, best MFMA density) --------------------
template<int BN, bool RELU>
__global__ __launch_bounds__(256) void gemm_tile(
    const unsigned short* __restrict__ A, const unsigned short* __restrict__ W,
    const float* __restrict__ bias,
    unsigned short* __restrict__ C, int M, int Nd, int K, int lda)
{
  constexpr int BM = 128, BK = 32;
  constexpr int MI = 4, NI = 4;
  __shared__ unsigned short sA[2][BM * BK];
  __shared__ unsigned short sB[2][BN * BK];

  const int w    = threadIdx.x >> 6;
  const int lane = threadIdx.x & 63;
  const int quad = lane >> 4;
  const int l16  = lane & 15;
  const int m0 = blockIdx.x * BM;
  const int n0 = blockIdx.y * BN;
  const int wrow0 = (w >> 1) * 64;
  const int wcol0 = (w & 1) * 64;

  const int aflat0 = w * 512 + lane * 8;
  const int ar0 = aflat0 >> 5, ac = aflat0 & 31;

  floatx4 acc[MI][NI] = {};

  for (int k0 = 0; k0 < K; k0 += 2 * BK) {
    __syncthreads();
    #pragma unroll
    for (int half = 0; half < 2; ++half) {
      const int kk = k0 + half * BK;
      #pragma unroll
      for (int c = 0; c < 2; ++c) {
        const int row = ar0 + c * 64;
        gl_lds16(A + (size_t)(m0 + row) * lda + kk + ac, &sA[half][(c * 4 + w) * 512]);
        gl_lds16(W + (size_t)(n0 + row) * K + kk + ac, &sB[half][(c * 4 + w) * 512]);
      }
    }
    __syncthreads();

    #pragma unroll
    for (int half = 0; half < 2; ++half) {
      short8 af[MI], bf[NI];
      #pragma unroll
      for (int mi = 0; mi < MI; ++mi)
        af[mi] = *(const short8*)&sA[half][(wrow0 + mi * 16 + l16) * BK + quad * 8];
      #pragma unroll
      for (int ni = 0; ni < NI; ++ni)
        bf[ni] = *(const short8*)&sB[half][(wcol0 + ni * 16 + l16) * BK + quad * 8];
      #pragma unroll
      for (int mi = 0; mi < MI; ++mi)
        #pragma unroll
        for (int ni = 0; ni < NI; ++ni)
          acc[mi][ni] = __builtin_amdgcn_mfma_f32_16x16x32_bf16(af[mi], bf[ni], acc[mi][ni], 0, 0, 0);
    }
  }

  #pragma unroll
  for (int ni = 0; ni < NI; ++ni) {
    const int col = n0 + wcol0 + ni * 16 + l16;
    const float bvv = bias[col];
    #pragma unroll
    for (int mi = 0; mi < MI; ++mi) {
      const int row0 = m0 + wrow0 + mi * 16 + quad * 4;
      #pragma unroll
      for (int i = 0; i < 4; ++i) {
        float v = acc[mi][ni][i] + bvv;
        if (RELU) v = fmaxf(v, 0.f);
        C[(size_t)(row0 + i) * Nd + col] = f2b(v);
      }
    }
  }
}

// -------- local gather attention: 1 block / query, kv row-interleaved -------
// XCD swizzle: blk -> n = (blk&7)*2048 + blk>>3 pins scenes {2x,2x+1} to XCD x
// -> per-XCD kv working set 2MB (fits 4MB L2); kills cross-XCD re-fetch.
__global__ __launch_bounds__(256) void attn_kernel(
    const unsigned short* __restrict__ q, const unsigned short* __restrict__ kv,
    const int* __restrict__ key_batch_cnt, const int* __restrict__ index_pair,
    const int* __restrict__ index_pair_batch,
    unsigned short* __restrict__ out)
{
  const int n = ((blockIdx.x & 7) << 11) | (blockIdx.x >> 3);
  const int t = threadIdx.x;
  __shared__ float s_q[DM];
  __shared__ int   s_gidx[LNEI];
  __shared__ float s_prob[NH][LNEI];
  __shared__ float s_out[2][DM];

  s_q[t] = b2f(q[(size_t)n * DM + t]);
  if (t < LNEI) {
    const int b = index_pair_batch[n];
    int off = 0;
    for (int i = 0; i < b; ++i) off += key_batch_cnt[i];
    const int ip = index_pair[(size_t)n * LNEI + t];
    s_gidx[t] = (ip < 0) ? -1 : (ip + off);
  }
  __syncthreads();

  {
    const int h = t >> 5;
    const int l = t & 31;
    const int g = s_gidx[l];

    floatx4 qv[8];
    #pragma unroll
    for (int c = 0; c < 8; ++c) qv[c] = *(const floatx4*)&s_q[h * DH + c * 4];

    float score = -1e9f;
    if (g >= 0) {
      const uint4_t* kp = (const uint4_t*)(kv + (size_t)g * 512 + h * DH);
      float acc = 0.f;
      #pragma unroll
      for (int c = 0; c < 4; ++c) {
        uint4_t d = kp[c];
        acc += lo16(d.x) * qv[c * 2][0] + hi16(d.x) * qv[c * 2][1]
             + lo16(d.y) * qv[c * 2][2] + hi16(d.y) * qv[c * 2][3]
             + lo16(d.z) * qv[c * 2 + 1][0] + hi16(d.z) * qv[c * 2 + 1][1]
             + lo16(d.w) * qv[c * 2 + 1][2] + hi16(d.w) * qv[c * 2 + 1][3];
      }
      score = acc * 0.17677669529663687f;  // 32^-0.5
    }

    float mx = score;
    #pragma unroll
    for (int msk = 16; msk >= 1; msk >>= 1) mx = fmaxf(mx, __shfl_xor(mx, msk, 64));
    const float e = __expf(score - mx);
    float sm = e;
    #pragma unroll
    for (int msk = 16; msk >= 1; msk >>= 1) sm += __shfl_xor(sm, msk, 64);
    s_prob[h][l] = e / sm;
  }
  __syncthreads();

  {
    const int jh  = t >> 7;
    const int h   = (t >> 4) & 7;
    const int dh2 = t & 15;
    float ax = 0.f, ay = 0.f;
    const unsigned short* vbase = kv + 256 + h * DH + dh2 * 2;
    #pragma unroll
    for (int j2 = 0; j2 < 16; ++j2) {
      const int j = jh * 16 + j2;
      int gj = s_gidx[j];
      gj = (gj < 0) ? 0 : gj;
      const float p = s_prob[h][j];
      const unsigned int d = *(const unsigned int*)(vbase + (size_t)gj * 512);
      ax += p * lo16(d);
      ay += p * hi16(d);
    }
    s_out[jh][h * DH + dh2 * 2]     = ax;
    s_out[jh][h * DH + dh2 * 2 + 1] = ay;
  }
  __syncthreads();

  out[(size_t)n * DM + t] = f2b(s_out[0][t] + s_out[1][t]);
}

// -------- residual + LayerNorm (wave-shuffle reduction) ---------------------
template<bool IN1F32, bool OUTF32>
__global__ __launch_bounds__(256) void ln_kernel(
    const void* __restrict__ in1, const unsigned short* __restrict__ in2,
    const float* __restrict__ g, const float* __restrict__ b,
    void* __restrict__ out)
{
  const int n = blockIdx.x;
  const int t = threadIdx.x;
  const int wv = t >> 6;
  __shared__ float part[8];

  float a1;
  if (IN1F32) a1 = ((const float*)in1)[(size_t)n * DM + t];
  else        a1 = b2f(((const unsigned short*)in1)[(size_t)n * DM + t]);
  const float a = a1 + b2f(in2[(size_t)n * DM + t]);

  float s = a;
  #pragma unroll
  for (int msk = 32; msk >= 1; msk >>= 1) s += __shfl_xor(s, msk, 64);
  if ((t & 63) == 0) part[wv] = s;
  __syncthreads();
  const float mean = (part[0] + part[1] + part[2] + part[3]) * (1.0f / DM);
  const float d = a - mean;
  float s2 = d * d;
  #pragma unroll
  for (int msk = 32; msk >= 1; msk >>= 1) s2 += __shfl_xor(s2, msk, 64);
  if ((t & 63) == 0) part[4 + wv] = s2;
  __syncthreads();
  const float var = (part[4] + part[5] + part[6] + part[7]) * (1.0f / DM);
  const float y = d * rsqrtf(var + 1e-5f) * g[t] + b[t];
  if (OUTF32) ((float*)out)[(size_t)n * DM + t] = y;
  else        ((unsigned short*)out)[(size_t)n * DM + t] = f2b(y);
}

extern "C" void kernel_launch(void* const* d_in, const int* in_sizes, int n_in,
                              void* d_out, int out_size, void* d_ws, size_t ws_size,
                              hipStream_t stream) {
  const float* tgt  = (const float*)d_in[0];
  const float* mem  = (const float*)d_in[1];
  const float* pos  = (const float*)d_in[2];
  const int* kbc    = (const int*)d_in[3];
  const int* ipair  = (const int*)d_in[4];
  const int* ipb    = (const int*)d_in[5];
  const float* Wq   = (const float*)d_in[6];
  const float* bq   = (const float*)d_in[7];
  const float* Wkc  = (const float*)d_in[8];
  const float* bkc  = (const float*)d_in[9];
  const float* Wkp  = (const float*)d_in[10];
  const float* bkp  = (const float*)d_in[11];
  const float* Wv   = (const float*)d_in[12];
  const float* bvp  = (const float*)d_in[13];
  const float* Wo   = (const float*)d_in[14];
  const float* bo   = (const float*)d_in[15];
  const float* W1   = (const float*)d_in[16];
  const float* b1   = (const float*)d_in[17];
  const float* W2   = (const float*)d_in[18];
  const float* b2   = (const float*)d_in[19];
  const float* g2   = (const float*)d_in[20];
  const float* be2  = (const float*)d_in[21];
  const float* g3   = (const float*)d_in[22];
  const float* be3  = (const float*)d_in[23];

  const size_t NB = (size_t)N_TOT * DM;
  unsigned short* ws = (unsigned short*)d_ws;
  unsigned short* tgt_b = ws;
  unsigned short* ao_b  = ws;
  unsigned short* t2_b  = ws + NB;
  unsigned short* mp_b  = ws + 2 * NB;
  unsigned short* x_b   = ws + 2 * NB;
  unsigned short* ff_b  = ws + 3 * NB;
  unsigned short* q_b   = ws + 4 * NB;
  unsigned short* h1_b  = ws + 4 * NB;
  unsigned short* kv_b  = ws + 5 * NB;
  unsigned short* wgt   = ws + 8 * NB;
  unsigned short* Wq_b  = wgt;
  unsigned short* Wkv_b = wgt + 65536;
  unsigned short* Wo_b  = wgt + 65536 + 262144;
  unsigned short* W1_b  = wgt + 2 * 65536 + 262144;
  unsigned short* W2_b  = wgt + 2 * 65536 + 2 * 262144;
  float* bias_kv = (float*)(wgt + 2 * 65536 + 3 * 262144);

  SegTable T;
  int beg = 0, i = 0;
  auto seg = [&](const float* s, unsigned short* d, int cols, int ostride, int ooff, int nelem) {
    T.s[i].src = s; T.s[i].dst = d; T.s[i].cols = cols;
    T.s[i].ostride = ostride; T.s[i].ooff = ooff; T.s[i].begin = beg;
    beg += nelem; ++i;
  };
  seg(tgt, tgt_b, DM, DM, 0,   (int)NB);
  seg(mem, mp_b,  DM, 512, 0,  (int)NB);
  seg(pos, mp_b,  DM, 512, DM, (int)NB);
  seg(Wq,  Wq_b,  DM, DM, 0,   65536);
  seg(Wkc, Wkv_b, DM, 512, 0,  65536);
  seg(Wkp, Wkv_b, DM, 512, DM, 65536);
  seg(Wv,  Wkv_b + (size_t)256 * 512, DM, 512, 0, 65536);
  seg(nullptr, Wkv_b + (size_t)256 * 512, DM, 512, DM, 65536);
  seg(Wo,  Wo_b,  DM, DM, 0,   65536);
  seg(W1,  W1_b,  DM, DM, 0,   262144);
  seg(W2,  W2_b,  DFF, DFF, 0, 262144);
  T.total = beg;

  dim3 blk(256);
  cvt_all<<<dim3(T.total / 1024 + 1), blk, 0, stream>>>(T, bias_kv, bkc, bkp, bvp);

  dim3 blk64(64);
  dim3 gQ(N_TOT / 32, DM / 64);      // 2048 blocks
  dim3 gKV(N_TOT / 32, 512 / 64);    // 4096 blocks
  dim3 gF(N_TOT / 128, DFF / 128);   // 1024 blocks (4-wave)

  gemm_w1<false><<<gQ, blk64, 0, stream>>>(tgt_b, Wq_b, bq, q_b, N_TOT, DM, DM, DM);
  gemm_w1<false><<<gKV, blk64, 0, stream>>>(mp_b, Wkv_b, bias_kv, kv_b, N_TOT, 512, 512, 512);
  attn_kernel<<<dim3(N_TOT), blk, 0, stream>>>(q_b, kv_b, kbc, ipair, ipb, ao_b);
  gemm_w1<false><<<gQ, blk64, 0, stream>>>(ao_b, Wo_b, bo, t2_b, N_TOT, DM, DM, DM);
  ln_kernel<true, false><<<dim3(N_TOT), blk, 0, stream>>>(tgt, t2_b, g2, be2, x_b);
  gemm_tile<128, true><<<gF, blk, 0, stream>>>(x_b, W1_b, b1, h1_b, N_TOT, DFF, DM, DM);
  gemm_w1<false><<<gQ, blk64, 0, stream>>>(h1_b, W2_b, b2, ff_b, N_TOT, DM, DFF, DFF);
  ln_kernel<false, true><<<dim3(N_TOT), blk, 0, stream>>>(x_b, ff_b, g3, be3, d_out);
}

// Round 8
// 273.354 us; speedup vs baseline: 1.0680x; 1.0680x over previous
//
#include <hip/hip_runtime.h>
#include <stdint.h>

#define N_TOT 16384
#define LNEI  32
#define DM    256
#define NH    8
#define DH    32
#define DFF   1024

typedef __attribute__((ext_vector_type(8))) short  short8;
typedef __attribute__((ext_vector_type(4))) float  floatx4;
typedef __attribute__((ext_vector_type(4))) unsigned short ushort4_t;
typedef __attribute__((ext_vector_type(4))) unsigned int uint4_t;

static __device__ __forceinline__ float b2f(unsigned short u) {
  union { unsigned int u; float f; } x; x.u = ((unsigned int)u) << 16; return x.f;
}
static __device__ __forceinline__ unsigned short f2b(float f) {
  union { float f; unsigned int u; } x; x.f = f;
  unsigned int r = x.u + 0x7fffu + ((x.u >> 16) & 1u);
  return (unsigned short)(r >> 16);
}
static __device__ __forceinline__ float lo16(unsigned int d) {
  union { unsigned int u; float f; } x; x.u = d << 16; return x.f;
}
static __device__ __forceinline__ float hi16(unsigned int d) {
  union { unsigned int u; float f; } x; x.u = d & 0xffff0000u; return x.f;
}

// -------- conversion pass: f32 -> bf16 into ws (strided dst, src=null -> 0) --
#define NSEG 11
struct Seg { const float* src; unsigned short* dst; int cols; int ostride; int ooff; int begin; };
struct SegTable { Seg s[NSEG]; int total; };

__global__ __launch_bounds__(256) void cvt_all(SegTable T, float* biaskv,
                                               const float* bkc, const float* bkp,
                                               const float* bv) {
  int e = (blockIdx.x * 256 + threadIdx.x) * 4;
  if (e >= T.total) {                       // trailing block: bias concat
    int c = e - T.total;
    #pragma unroll
    for (int j = 0; j < 4; ++j, ++c)
      if (c < 512) biaskv[c] = (c < 256) ? (bkc[c] + bkp[c]) : bv[c - 256];
    return;
  }
  int si = 0;
  #pragma unroll
  for (int i = 1; i < NSEG; ++i) if (e >= T.s[i].begin) si = i;
  const Seg s = T.s[si];
  const int le = e - s.begin;
  const int row = le / s.cols;
  const int col = le - row * s.cols;
  floatx4 v = {0.f, 0.f, 0.f, 0.f};
  if (s.src) v = *(const floatx4*)(s.src + le);
  ushort4_t o;
  o.x = f2b(v[0]); o.y = f2b(v[1]); o.z = f2b(v[2]); o.w = f2b(v[3]);
  *(ushort4_t*)(s.dst + (size_t)row * s.ostride + s.ooff + col) = o;
}

static __device__ __forceinline__ void gl_lds16(const unsigned short* g, unsigned short* l) {
  __builtin_amdgcn_global_load_lds(
      (const __attribute__((address_space(1))) unsigned int*)g,
      (__attribute__((address_space(3))) unsigned int*)l, 16, 0, 0);
}

// -------- tiled bf16 GEMM (r6 version): C = A @ W^T + bias, opt ReLU --------
// BM=128, BK=32x2 per barrier pair, BN in {64,128}. global_load_lds width=16.
// MFMA 16x16x32; A-frag lane: A[r=l16][k=quad*8..+8]; C/D col=l16, row=quad*4+i.
template<int BN, bool RELU>
__global__ __launch_bounds__(256) void gemm_tile(
    const unsigned short* __restrict__ A, const unsigned short* __restrict__ W,
    const float* __restrict__ bias,
    unsigned short* __restrict__ C, int M, int Nd, int K, int lda)
{
  constexpr int BM = 128, BK = 32;
  constexpr int MI = (BN == 128) ? 4 : 2;
  constexpr int NI = 4;
  __shared__ unsigned short sA[2][BM * BK];
  __shared__ unsigned short sB[2][BN * BK];

  const int w    = threadIdx.x >> 6;
  const int lane = threadIdx.x & 63;
  const int quad = lane >> 4;
  const int l16  = lane & 15;
  const int m0 = blockIdx.x * BM;
  const int n0 = blockIdx.y * BN;
  const int wrow0 = (BN == 128) ? (w >> 1) * 64 : w * 32;
  const int wcol0 = (BN == 128) ? (w & 1) * 64 : 0;

  const int aflat0 = w * 512 + lane * 8;
  const int ar0 = aflat0 >> 5, ac = aflat0 & 31;

  floatx4 acc[MI][NI] = {};

  for (int k0 = 0; k0 < K; k0 += 2 * BK) {
    __syncthreads();
    #pragma unroll
    for (int half = 0; half < 2; ++half) {
      const int kk = k0 + half * BK;
      #pragma unroll
      for (int c = 0; c < 2; ++c) {
        const int row = ar0 + c * 64;
        gl_lds16(A + (size_t)(m0 + row) * lda + kk + ac, &sA[half][(c * 4 + w) * 512]);
      }
      if (BN == 128) {
        #pragma unroll
        for (int c = 0; c < 2; ++c) {
          const int row = ar0 + c * 64;
          gl_lds16(W + (size_t)(n0 + row) * K + kk + ac, &sB[half][(c * 4 + w) * 512]);
        }
      } else {
        gl_lds16(W + (size_t)(n0 + ar0) * K + kk + ac, &sB[half][w * 512]);
      }
    }
    __syncthreads();

    #pragma unroll
    for (int half = 0; half < 2; ++half) {
      short8 af[MI], bf[NI];
      #pragma unroll
      for (int mi = 0; mi < MI; ++mi)
        af[mi] = *(const short8*)&sA[half][(wrow0 + mi * 16 + l16) * BK + quad * 8];
      #pragma unroll
      for (int ni = 0; ni < NI; ++ni)
        bf[ni] = *(const short8*)&sB[half][(wcol0 + ni * 16 + l16) * BK + quad * 8];
      #pragma unroll
      for (int mi = 0; mi < MI; ++mi)
        #pragma unroll
        for (int ni = 0; ni < NI; ++ni)
          acc[mi][ni] = __builtin_amdgcn_mfma_f32_16x16x32_bf16(af[mi], bf[ni], acc[mi][ni], 0, 0, 0);
    }
  }

  #pragma unroll
  for (int ni = 0; ni < NI; ++ni) {
    const int col = n0 + wcol0 + ni * 16 + l16;
    const float bvv = bias[col];
    #pragma unroll
    for (int mi = 0; mi < MI; ++mi) {
      const int row0 = m0 + wrow0 + mi * 16 + quad * 4;
      #pragma unroll
      for (int i = 0; i < 4; ++i) {
        float v = acc[mi][ni][i] + bvv;
        if (RELU) v = fmaxf(v, 0.f);
        C[(size_t)(row0 + i) * Nd + col] = f2b(v);
      }
    }
  }
}

// -------- local gather attention: 1 block / query, kv row-interleaved -------
// kv[key] = [k(256) | v(256)], row stride 512 shorts.
// XCD swizzle: n = (blk&7)*2048 + blk>>3 -> per-XCD kv working set ~2MB in L2.
// Phase A (coalesced QK): t=(j=t>>3, c8=t&7). Each thread loads 4x16B
//   CONTIGUOUS chunks of k-row j (8 lanes cover 128B contiguous -> 8 cache
//   lines per wave-instr instead of 64), dots against q chunks from LDS
//   (same-address broadcast, free), then shfl_xor(1,2) folds the 4 partials
//   per (j,h). Chunk c=c8+8i -> h=2i+(c8>=4).
// Phase B: t=(jh,h,dh2): coalesced dword loads of v + FMA, 2-way LDS combine.
__global__ __launch_bounds__(256) void attn_kernel(
    const unsigned short* __restrict__ q, const unsigned short* __restrict__ kv,
    const int* __restrict__ key_batch_cnt, const int* __restrict__ index_pair,
    const int* __restrict__ index_pair_batch,
    unsigned short* __restrict__ out)
{
  const int n = ((blockIdx.x & 7) << 11) | (blockIdx.x >> 3);
  const int t = threadIdx.x;
  __shared__ float s_q[DM];
  __shared__ int   s_gidx[LNEI];
  __shared__ float s_score[NH][LNEI];
  __shared__ float s_prob[NH][LNEI];
  __shared__ float s_out[2][DM];

  s_q[t] = b2f(q[(size_t)n * DM + t]);
  if (t < LNEI) {
    const int b = index_pair_batch[n];
    int off = 0;
    for (int i = 0; i < b; ++i) off += key_batch_cnt[i];
    const int ip = index_pair[(size_t)n * LNEI + t];
    s_gidx[t] = (ip < 0) ? -1 : (ip + off);
  }
  __syncthreads();

  // Phase A
  {
    const int j  = t >> 3;
    const int c8 = t & 7;
    const int g  = s_gidx[j];
    const int gl = (g < 0) ? 0 : g;
    const unsigned short* kbase = kv + (size_t)gl * 512;

    float part[4];
    #pragma unroll
    for (int i = 0; i < 4; ++i) {
      const int c = c8 + i * 8;                       // 16B chunk, 0..31
      const uint4_t d = *(const uint4_t*)(kbase + c * 8);
      const float* qp = &s_q[c * 8];
      part[i] = lo16(d.x) * qp[0] + hi16(d.x) * qp[1]
              + lo16(d.y) * qp[2] + hi16(d.y) * qp[3]
              + lo16(d.z) * qp[4] + hi16(d.z) * qp[5]
              + lo16(d.w) * qp[6] + hi16(d.w) * qp[7];
    }
    #pragma unroll
    for (int i = 0; i < 4; ++i) {
      part[i] += __shfl_xor(part[i], 1, 64);
      part[i] += __shfl_xor(part[i], 2, 64);
    }
    if ((c8 & 3) == 0) {
      const int hodd = c8 >> 2;
      #pragma unroll
      for (int i = 0; i < 4; ++i)
        s_score[2 * i + hodd][j] =
            (g < 0) ? -1e9f : part[i] * 0.17677669529663687f;  // 32^-0.5
    }
  }
  __syncthreads();

  // softmax: t = (h, l)
  {
    const int h = t >> 5;
    const int l = t & 31;
    const float sc = s_score[h][l];
    float mx = sc;
    #pragma unroll
    for (int msk = 16; msk >= 1; msk >>= 1) mx = fmaxf(mx, __shfl_xor(mx, msk, 64));
    const float e = __expf(sc - mx);
    float sm = e;
    #pragma unroll
    for (int msk = 16; msk >= 1; msk >>= 1) sm += __shfl_xor(sm, msk, 64);
    s_prob[h][l] = e / sm;
  }
  __syncthreads();

  // Phase B
  {
    const int jh  = t >> 7;
    const int h   = (t >> 4) & 7;
    const int dh2 = t & 15;
    float ax = 0.f, ay = 0.f;
    const unsigned short* vbase = kv + 256 + h * DH + dh2 * 2;
    #pragma unroll
    for (int j2 = 0; j2 < 16; ++j2) {
      const int j = jh * 16 + j2;
      int gj = s_gidx[j];
      gj = (gj < 0) ? 0 : gj;
      const float p = s_prob[h][j];
      const unsigned int d = *(const unsigned int*)(vbase + (size_t)gj * 512);
      ax += p * lo16(d);
      ay += p * hi16(d);
    }
    s_out[jh][h * DH + dh2 * 2]     = ax;
    s_out[jh][h * DH + dh2 * 2 + 1] = ay;
  }
  __syncthreads();

  out[(size_t)n * DM + t] = f2b(s_out[0][t] + s_out[1][t]);
}

// -------- residual + LayerNorm (wave-shuffle reduction) ---------------------
template<bool IN1F32, bool OUTF32>
__global__ __launch_bounds__(256) void ln_kernel(
    const void* __restrict__ in1, const unsigned short* __restrict__ in2,
    const float* __restrict__ g, const float* __restrict__ b,
    void* __restrict__ out)
{
  const int n = blockIdx.x;
  const int t = threadIdx.x;
  const int wv = t >> 6;
  __shared__ float part[8];

  float a1;
  if (IN1F32) a1 = ((const float*)in1)[(size_t)n * DM + t];
  else        a1 = b2f(((const unsigned short*)in1)[(size_t)n * DM + t]);
  const float a = a1 + b2f(in2[(size_t)n * DM + t]);

  float s = a;
  #pragma unroll
  for (int msk = 32; msk >= 1; msk >>= 1) s += __shfl_xor(s, msk, 64);
  if ((t & 63) == 0) part[wv] = s;
  __syncthreads();
  const float mean = (part[0] + part[1] + part[2] + part[3]) * (1.0f / DM);
  const float d = a - mean;
  float s2 = d * d;
  #pragma unroll
  for (int msk = 32; msk >= 1; msk >>= 1) s2 += __shfl_xor(s2, msk, 64);
  if ((t & 63) == 0) part[4 + wv] = s2;
  __syncthreads();
  const float var = (part[4] + part[5] + part[6] + part[7]) * (1.0f / DM);
  const float y = d * rsqrtf(var + 1e-5f) * g[t] + b[t];
  if (OUTF32) ((float*)out)[(size_t)n * DM + t] = y;
  else        ((unsigned short*)out)[(size_t)n * DM + t] = f2b(y);
}

extern "C" void kernel_launch(void* const* d_in, const int* in_sizes, int n_in,
                              void* d_out, int out_size, void* d_ws, size_t ws_size,
                              hipStream_t stream) {
  const float* tgt  = (const float*)d_in[0];
  const float* mem  = (const float*)d_in[1];
  const float* pos  = (const float*)d_in[2];
  const int* kbc    = (const int*)d_in[3];
  const int* ipair  = (const int*)d_in[4];
  const int* ipb    = (const int*)d_in[5];
  const float* Wq   = (const float*)d_in[6];
  const float* bq   = (const float*)d_in[7];
  const float* Wkc  = (const float*)d_in[8];
  const float* bkc  = (const float*)d_in[9];
  const float* Wkp  = (const float*)d_in[10];
  const float* bkp  = (const float*)d_in[11];
  const float* Wv   = (const float*)d_in[12];
  const float* bvp  = (const float*)d_in[13];
  const float* Wo   = (const float*)d_in[14];
  const float* bo   = (const float*)d_in[15];
  const float* W1   = (const float*)d_in[16];
  const float* b1   = (const float*)d_in[17];
  const float* W2   = (const float*)d_in[18];
  const float* b2   = (const float*)d_in[19];
  const float* g2   = (const float*)d_in[20];
  const float* be2  = (const float*)d_in[21];
  const float* g3   = (const float*)d_in[22];
  const float* be3  = (const float*)d_in[23];

  const size_t NB = (size_t)N_TOT * DM;
  unsigned short* ws = (unsigned short*)d_ws;
  unsigned short* tgt_b = ws;
  unsigned short* ao_b  = ws;
  unsigned short* t2_b  = ws + NB;
  unsigned short* mp_b  = ws + 2 * NB;
  unsigned short* x_b   = ws + 2 * NB;
  unsigned short* ff_b  = ws + 3 * NB;
  unsigned short* q_b   = ws + 4 * NB;
  unsigned short* h1_b  = ws + 4 * NB;
  unsigned short* kv_b  = ws + 5 * NB;
  unsigned short* wgt   = ws + 8 * NB;
  unsigned short* Wq_b  = wgt;
  unsigned short* Wkv_b = wgt + 65536;
  unsigned short* Wo_b  = wgt + 65536 + 262144;
  unsigned short* W1_b  = wgt + 2 * 65536 + 262144;
  unsigned short* W2_b  = wgt + 2 * 65536 + 2 * 262144;
  float* bias_kv = (float*)(wgt + 2 * 65536 + 3 * 262144);

  SegTable T;
  int beg = 0, i = 0;
  auto seg = [&](const float* s, unsigned short* d, int cols, int ostride, int ooff, int nelem) {
    T.s[i].src = s; T.s[i].dst = d; T.s[i].cols = cols;
    T.s[i].ostride = ostride; T.s[i].ooff = ooff; T.s[i].begin = beg;
    beg += nelem; ++i;
  };
  seg(tgt, tgt_b, DM, DM, 0,   (int)NB);
  seg(mem, mp_b,  DM, 512, 0,  (int)NB);
  seg(pos, mp_b,  DM, 512, DM, (int)NB);
  seg(Wq,  Wq_b,  DM, DM, 0,   65536);
  seg(Wkc, Wkv_b, DM, 512, 0,  65536);
  seg(Wkp, Wkv_b, DM, 512, DM, 65536);
  seg(Wv,  Wkv_b + (size_t)256 * 512, DM, 512, 0, 65536);
  seg(nullptr, Wkv_b + (size_t)256 * 512, DM, 512, DM, 65536);
  seg(Wo,  Wo_b,  DM, DM, 0,   65536);
  seg(W1,  W1_b,  DM, DM, 0,   262144);
  seg(W2,  W2_b,  DFF, DFF, 0, 262144);
  T.total = beg;

  dim3 blk(256);
  cvt_all<<<dim3(T.total / 1024 + 1), blk, 0, stream>>>(T, bias_kv, bkc, bkp, bvp);

  dim3 gQ(N_TOT / 128, DM / 64);     // Nd=256, BN=64 -> 512 blocks
  dim3 gKV(N_TOT / 128, 512 / 64);   // Nd=512, BN=64 -> 1024 blocks
  dim3 gF(N_TOT / 128, DFF / 128);   // Nd=1024, BN=128 -> 1024 blocks

  gemm_tile<64, false><<<gQ, blk, 0, stream>>>(tgt_b, Wq_b, bq, q_b, N_TOT, DM, DM, DM);
  gemm_tile<64, false><<<gKV, blk, 0, stream>>>(mp_b, Wkv_b, bias_kv, kv_b, N_TOT, 512, 512, 512);
  attn_kernel<<<dim3(N_TOT), blk, 0, stream>>>(q_b, kv_b, kbc, ipair, ipb, ao_b);
  gemm_tile<64, false><<<gQ, blk, 0, stream>>>(ao_b, Wo_b, bo, t2_b, N_TOT, DM, DM, DM);
  ln_kernel<true, false><<<dim3(N_TOT), blk, 0, stream>>>(tgt, t2_b, g2, be2, x_b);
  gemm_tile<128, true><<<gF, blk, 0, stream>>>(x_b, W1_b, b1, h1_b, N_TOT, DFF, DM, DM);
  gemm_tile<64, false><<<gQ, blk, 0, stream>>>(h1_b, W2_b, b2, ff_b, N_TOT, DM, DFF, DFF);
  ln_kernel<false, true><<<dim3(N_TOT), blk, 0, stream>>>(x_b, ff_b, g3, be3, d_out);
}